// Round 1
// baseline (9742.914 us; speedup 1.0000x reference)
//
#include <hip/hip_runtime.h>
#include <math.h>

#define NL    12
#define HDIM  768
#define NHEAD 12
#define DHEAD 64
#define FFI   2048
#define SEQ   512
#define BATCH 4
#define NROWS 2048          /* SEQ*BATCH */
#define QKW   1536          /* 2*HDIM */
#define SCALE 0.07216878364870323f
#define LNEPS 1e-7f

/* ---- workspace offsets (in floats) ---- */
#define OH    0u         /* h       2048x768            */
#define OQK   1572864u   /* qk      2048x1536           */
#define OV    4718592u   /* v       2048x768            */
#define OPOS  6291456u   /* pospad  64x1536             */
#define OCP   6389760u   /* CP      48x512x63           */
#define OPC   7938048u   /* PC      48x63x512           */
#define OCTX  9486336u   /* ctx     2048x768            */
#define OT1   11059200u  /* t1      2048x768            */
#define OXM   12632064u  /* x_mid   2048x768            */
#define OHH   14204928u  /* hh      2048x768            */
#define ORP   15777792u  /* relpad  64x768              */
/* FFN phase aliases (attention buffers dead by then) */
#define OU1   0u         /* u1      2048x4096           */
#define OU2   8388608u   /* u2      2048x2048           */

__device__ __forceinline__ float block_reduce_sum_256(float v, float* sred) {
    #pragma unroll
    for (int off = 32; off > 0; off >>= 1) v += __shfl_down(v, off, 64);
    const int w = threadIdx.x >> 6;
    if ((threadIdx.x & 63) == 0) sred[w] = v;
    __syncthreads();
    float r = sred[0] + sred[1] + sred[2] + sred[3];
    __syncthreads();
    return r;
}

/* pad relative_embedding (63x768) to 64x768 with a zero row */
__global__ __launch_bounds__(256) void pad_copy(const float* __restrict__ rel,
                                                float* __restrict__ relpad) {
    int i = blockIdx.x * 256 + threadIdx.x;          /* 0 .. 64*768-1 */
    relpad[i] = (i < 63 * HDIM) ? rel[i] : 0.f;
}

/* LayerNorm without affine: one block per row of 768 */
__global__ __launch_bounds__(256) void ln_rows(const float* __restrict__ in,
                                               float* __restrict__ out) {
    __shared__ float sred[4];
    const int row = blockIdx.x;
    const float* r = in + (size_t)row * HDIM;
    float v[3];
    #pragma unroll
    for (int i = 0; i < 3; ++i) v[i] = r[threadIdx.x + i * 256];
    float s = v[0] + v[1] + v[2];
    s = block_reduce_sum_256(s, sred);
    const float mean = s * (1.0f / HDIM);
    float q = 0.f;
    #pragma unroll
    for (int i = 0; i < 3; ++i) { float d = v[i] - mean; q += d * d; }
    q = block_reduce_sum_256(q, sred);
    const float rstd = 1.0f / sqrtf(q * (1.0f / HDIM) + LNEPS);
    float* o = out + (size_t)row * HDIM;
    #pragma unroll
    for (int i = 0; i < 3; ++i) o[threadIdx.x + i * 256] = (v[i] - mean) * rstd;
}

/* C[M,N] = A[M,K] @ Bw[N,K]^T (+bias[N]) (+Res[M,N]); 64x64 tile, 4x4/thread */
template<bool HB, bool HR>
__global__ __launch_bounds__(256)
void gemm_tn(const float* __restrict__ A, const float* __restrict__ Bw,
             const float* __restrict__ bias, const float* __restrict__ Res,
             float* __restrict__ C, int M, int N, int K) {
    __shared__ float As[16][68];
    __shared__ float Bs[16][68];
    const int bm = blockIdx.y * 64;
    const int bn = blockIdx.x * 64;
    const int ty = threadIdx.x >> 4;        /* 0..15 */
    const int tx = threadIdx.x & 15;
    const int lr = threadIdx.x >> 2;        /* 0..63 */
    const int lc = (threadIdx.x & 3) * 4;   /* 0,4,8,12 */
    const float* Aptr = A + (size_t)(bm + lr) * K + lc;
    const float* Bptr = Bw + (size_t)(bn + lr) * K + lc;
    float acc[4][4] = {};
    for (int kt = 0; kt < K; kt += 16) {
        float4 a4 = *(const float4*)(Aptr + kt);
        float4 b4 = *(const float4*)(Bptr + kt);
        As[lc + 0][lr] = a4.x; As[lc + 1][lr] = a4.y;
        As[lc + 2][lr] = a4.z; As[lc + 3][lr] = a4.w;
        Bs[lc + 0][lr] = b4.x; Bs[lc + 1][lr] = b4.y;
        Bs[lc + 2][lr] = b4.z; Bs[lc + 3][lr] = b4.w;
        __syncthreads();
        #pragma unroll
        for (int k = 0; k < 16; ++k) {
            float4 av = *(const float4*)&As[k][ty * 4];
            float4 bv = *(const float4*)&Bs[k][tx * 4];
            float a[4] = {av.x, av.y, av.z, av.w};
            float b[4] = {bv.x, bv.y, bv.z, bv.w};
            #pragma unroll
            for (int i = 0; i < 4; ++i)
                #pragma unroll
                for (int j = 0; j < 4; ++j) acc[i][j] += a[i] * b[j];
        }
        __syncthreads();
    }
    #pragma unroll
    for (int i = 0; i < 4; ++i) {
        const int r = bm + ty * 4 + i;
        #pragma unroll
        for (int j = 0; j < 4; ++j) {
            const int c = bn + tx * 4 + j;
            float v = acc[i][j];
            if (HB) v += bias[c];
            if (HR) v += Res[(size_t)r * N + c];
            C[(size_t)r * N + c] = v;
        }
    }
}

/* CP[bh,q,kb] = scale * sum_d q[b,h,q,d]*kpos[kb,h,d] */
__global__ __launch_bounds__(256)
void cp_kernel(const float* __restrict__ qk, const float* __restrict__ pos,
               float* __restrict__ CP) {
    const int bh = blockIdx.x;
    const int b = bh / NHEAD, hd = bh % NHEAD;
    const int qt = blockIdx.y * 64;
    __shared__ float kp[64][65];
    __shared__ float qs[64][65];
    for (int i = threadIdx.x; i < 64 * 64; i += 256) {
        int kb = i >> 6, d = i & 63;
        kp[kb][d] = (kb < 63) ? pos[(size_t)kb * QKW + HDIM + hd * 64 + d] : 0.f;
    }
    for (int i = threadIdx.x; i < 64 * 64; i += 256) {
        int q = i >> 6, d = i & 63;
        qs[q][d] = qk[((size_t)(qt + q) * BATCH + b) * QKW + hd * 64 + d];
    }
    __syncthreads();
    const int ql = threadIdx.x >> 2;
    const int kb0 = threadIdx.x & 3;
    float s[16] = {};
    #pragma unroll
    for (int d = 0; d < 64; ++d) {
        float qr = qs[ql][d];
        #pragma unroll
        for (int jj = 0; jj < 16; ++jj) s[jj] += qr * kp[kb0 + jj * 4][d];
    }
    #pragma unroll
    for (int jj = 0; jj < 16; ++jj) {
        int kb = kb0 + jj * 4;
        if (kb < 63)
            CP[((size_t)bh * SEQ + qt + ql) * 63 + kb] = s[jj] * SCALE;
    }
}

/* PC[bh,qb,k] = scale * sum_d k[b,h,k,d]*qpos[qb,h,d] */
__global__ __launch_bounds__(256)
void pc_kernel(const float* __restrict__ qk, const float* __restrict__ pos,
               float* __restrict__ PC) {
    const int bh = blockIdx.x;
    const int b = bh / NHEAD, hd = bh % NHEAD;
    const int kt = blockIdx.y * 64;
    __shared__ float qp[64][65];
    __shared__ float ks[64][65];
    for (int i = threadIdx.x; i < 64 * 64; i += 256) {
        int qb = i >> 6, d = i & 63;
        qp[qb][d] = (qb < 63) ? pos[(size_t)qb * QKW + hd * 64 + d] : 0.f;
    }
    for (int i = threadIdx.x; i < 64 * 64; i += 256) {
        int kl = i >> 6, d = i & 63;
        ks[kl][d] = qk[((size_t)(kt + kl) * BATCH + b) * QKW + HDIM + hd * 64 + d];
    }
    __syncthreads();
    const int kl = threadIdx.x & 63;
    const int qb0 = threadIdx.x >> 6;
    float s[16] = {};
    #pragma unroll
    for (int d = 0; d < 64; ++d) {
        float kr = ks[kl][d];
        #pragma unroll
        for (int jj = 0; jj < 16; ++jj) s[jj] += kr * qp[qb0 + jj * 4][d];
    }
    #pragma unroll
    for (int jj = 0; jj < 16; ++jj) {
        int qb = qb0 + jj * 4;
        if (qb < 63)
            PC[((size_t)bh * 63 + qb) * SEQ + kt + kl] = s[jj] * SCALE;
    }
}

/* scores + rel-pos gathers + mask + softmax -> probs (written to d_out) */
__global__ __launch_bounds__(256)
void scores_softmax(const float* __restrict__ qk, const float* __restrict__ CP,
                    const float* __restrict__ PC, const int* __restrict__ idx,
                    const unsigned char* __restrict__ mask,
                    float* __restrict__ probs) {
    const int bh = blockIdx.x;
    const int b = bh / NHEAD, hd = bh % NHEAD;
    const int qbase = blockIdx.y * 16;
    const int row = threadIdx.x >> 4;   /* 0..15 */
    const int ln = threadIdx.x & 15;
    __shared__ float qs[16][65];
    __shared__ float ks[64][65];
    for (int i = threadIdx.x; i < 16 * 64; i += 256) {
        int q = i >> 6, d = i & 63;
        qs[q][d] = qk[((size_t)(qbase + q) * BATCH + b) * QKW + hd * 64 + d];
    }
    float sc[32];
    for (int kt = 0; kt < 8; ++kt) {
        __syncthreads();
        for (int i = threadIdx.x; i < 64 * 64; i += 256) {
            int kl = i >> 6, d = i & 63;
            ks[kl][d] = qk[((size_t)(kt * 64 + kl) * BATCH + b) * QKW + HDIM + hd * 64 + d];
        }
        __syncthreads();
        float s0 = 0.f, s1 = 0.f, s2 = 0.f, s3 = 0.f;
        #pragma unroll
        for (int d = 0; d < 64; ++d) {
            float qr = qs[row][d];
            s0 += qr * ks[ln +  0][d];
            s1 += qr * ks[ln + 16][d];
            s2 += qr * ks[ln + 32][d];
            s3 += qr * ks[ln + 48][d];
        }
        sc[kt * 4 + 0] = s0; sc[kt * 4 + 1] = s1;
        sc[kt * 4 + 2] = s2; sc[kt * 4 + 3] = s3;
    }
    const int* idxrow = idx + (size_t)(qbase + row) * SEQ;
    const float* CProw = CP + ((size_t)bh * SEQ + qbase + row) * 63;
    #pragma unroll
    for (int j = 0; j < 32; ++j) {
        const int col = (j >> 2) * 64 + (j & 3) * 16 + ln;
        const int ix = idxrow[col];
        float s = sc[j] * SCALE + CProw[ix] + PC[((size_t)bh * 63 + ix) * SEQ + col];
        if (mask[b * SEQ + col]) s = -INFINITY;
        sc[j] = s;
    }
    float mx = sc[0];
    #pragma unroll
    for (int j = 1; j < 32; ++j) mx = fmaxf(mx, sc[j]);
    #pragma unroll
    for (int off = 1; off < 16; off <<= 1) mx = fmaxf(mx, __shfl_xor(mx, off, 16));
    float sum = 0.f;
    #pragma unroll
    for (int j = 0; j < 32; ++j) { float e = expf(sc[j] - mx); sc[j] = e; sum += e; }
    #pragma unroll
    for (int off = 1; off < 16; off <<= 1) sum += __shfl_xor(sum, off, 16);
    const float inv = 1.0f / sum;
    float* prow = probs + ((size_t)bh * SEQ + qbase + row) * SEQ;
    #pragma unroll
    for (int j = 0; j < 32; ++j) {
        const int col = (j >> 2) * 64 + (j & 3) * 16 + ln;
        float p = sc[j] * inv;
        if (mask[b * SEQ + col]) p = 0.f;
        prow[col] = p;
    }
}

/* ctx[q,b, h*64+d] = sum_k probs[bh,q,k] * v[b,h,k,d] */
__global__ __launch_bounds__(256)
void ctx_kernel(const float* __restrict__ probs, const float* __restrict__ vbuf,
                float* __restrict__ ctx) {
    const int bh = blockIdx.x;
    const int b = bh / NHEAD, hd = bh % NHEAD;
    const int qt = blockIdx.y * 64;
    __shared__ float ps[32][65];
    __shared__ float vs[32][65];
    const int ty = threadIdx.x >> 4, tx = threadIdx.x & 15;
    float acc[4][4] = {};
    const float* prow = probs + ((size_t)bh * SEQ + qt) * SEQ;
    for (int kt = 0; kt < 16; ++kt) {
        for (int i = threadIdx.x; i < 64 * 32; i += 256) {
            int q = i >> 5, kk = i & 31;
            ps[kk][q] = prow[(size_t)q * SEQ + kt * 32 + kk];
        }
        for (int i = threadIdx.x; i < 32 * 64; i += 256) {
            int kk = i >> 6, d = i & 63;
            vs[kk][d] = vbuf[((size_t)(kt * 32 + kk) * BATCH + b) * HDIM + hd * 64 + d];
        }
        __syncthreads();
        #pragma unroll
        for (int k = 0; k < 32; ++k) {
            float a[4], bb[4];
            #pragma unroll
            for (int i = 0; i < 4; ++i) a[i] = ps[k][ty * 4 + i];
            #pragma unroll
            for (int j = 0; j < 4; ++j) bb[j] = vs[k][tx * 4 + j];
            #pragma unroll
            for (int i = 0; i < 4; ++i)
                #pragma unroll
                for (int j = 0; j < 4; ++j) acc[i][j] += a[i] * bb[j];
        }
        __syncthreads();
    }
    #pragma unroll
    for (int i = 0; i < 4; ++i)
        #pragma unroll
        for (int j = 0; j < 4; ++j)
            ctx[((size_t)(qt + ty * 4 + i) * BATCH + b) * HDIM + hd * 64 + tx * 4 + j] = acc[i][j];
}

/* x_mid = x + ln(t1)*g + b ; hh = ln(x_mid) */
__global__ __launch_bounds__(256)
void post_attn(const float* __restrict__ t1, const float* __restrict__ xprev,
               const float* __restrict__ g, const float* __restrict__ bb,
               float* __restrict__ xmid, float* __restrict__ hh) {
    __shared__ float sred[4];
    const int row = blockIdx.x;
    const float* tr = t1 + (size_t)row * HDIM;
    float v[3];
    #pragma unroll
    for (int i = 0; i < 3; ++i) v[i] = tr[threadIdx.x + i * 256];
    float s = v[0] + v[1] + v[2];
    s = block_reduce_sum_256(s, sred);
    const float mean = s * (1.0f / HDIM);
    float q = 0.f;
    #pragma unroll
    for (int i = 0; i < 3; ++i) { float d = v[i] - mean; q += d * d; }
    q = block_reduce_sum_256(q, sred);
    const float rstd = 1.0f / sqrtf(q * (1.0f / HDIM) + LNEPS);
    float xm[3];
    #pragma unroll
    for (int i = 0; i < 3; ++i) {
        const int c = threadIdx.x + i * 256;
        xm[i] = xprev[(size_t)row * HDIM + c] + ((v[i] - mean) * rstd * g[c] + bb[c]);
        xmid[(size_t)row * HDIM + c] = xm[i];
    }
    float s2 = xm[0] + xm[1] + xm[2];
    s2 = block_reduce_sum_256(s2, sred);
    const float mean2 = s2 * (1.0f / HDIM);
    float q2 = 0.f;
    #pragma unroll
    for (int i = 0; i < 3; ++i) { float d = xm[i] - mean2; q2 += d * d; }
    q2 = block_reduce_sum_256(q2, sred);
    const float rstd2 = 1.0f / sqrtf(q2 * (1.0f / HDIM) + LNEPS);
    #pragma unroll
    for (int i = 0; i < 3; ++i)
        hh[(size_t)row * HDIM + threadIdx.x + i * 256] = (xm[i] - mean2) * rstd2;
}

/* u2 = ln( a * gelu_new(gate) ) over I=2048 */
__global__ __launch_bounds__(256)
void act_ln(const float* __restrict__ u1, float* __restrict__ u2) {
    __shared__ float sred[4];
    const int row = blockIdx.x;
    const float* r = u1 + (size_t)row * (2 * FFI);
    float t[8];
    #pragma unroll
    for (int i = 0; i < 8; ++i) {
        const int c = threadIdx.x + i * 256;
        const float a  = r[c];
        const float gt = r[FFI + c];
        const float x3 = gt + 0.044715f * gt * gt * gt;
        const float th = tanhf(0.7978845608028654f * x3);
        t[i] = a * 0.5f * gt * (1.0f + th);
    }
    float s = 0.f;
    #pragma unroll
    for (int i = 0; i < 8; ++i) s += t[i];
    s = block_reduce_sum_256(s, sred);
    const float mean = s * (1.0f / FFI);
    float q = 0.f;
    #pragma unroll
    for (int i = 0; i < 8; ++i) { float d = t[i] - mean; q += d * d; }
    q = block_reduce_sum_256(q, sred);
    const float rstd = 1.0f / sqrtf(q * (1.0f / FFI) + LNEPS);
    #pragma unroll
    for (int i = 0; i < 8; ++i)
        u2[(size_t)row * FFI + threadIdx.x + i * 256] = (t[i] - mean) * rstd;
}

extern "C" void kernel_launch(void* const* d_in, const int* in_sizes, int n_in,
                              void* d_out, int out_size, void* d_ws, size_t ws_size,
                              hipStream_t stream) {
    const float*         x0   = (const float*)d_in[0];
    const unsigned char* mask = (const unsigned char*)d_in[1];
    const float*         rel  = (const float*)d_in[2];
    const int*           pidx = (const int*)d_in[3];
    const float*         Wqk  = (const float*)d_in[4];
    const float*         bqk  = (const float*)d_in[5];
    const float*         Wv   = (const float*)d_in[6];
    const float*         bv   = (const float*)d_in[7];
    const float*         Wo   = (const float*)d_in[8];
    const float*         bo   = (const float*)d_in[9];
    const float*         lng  = (const float*)d_in[10];
    const float*         lnb  = (const float*)d_in[11];
    const float*         W1   = (const float*)d_in[12];
    const float*         W2   = (const float*)d_in[13];

    float* out = (float*)d_out;
    float* ws  = (float*)d_ws;
    float* probs_out = out + (size_t)(NL + 1) * NROWS * HDIM;   /* +20447232 */

    /* hidden_stack[0] = input */
    hipMemcpyAsync(out, x0, (size_t)NROWS * HDIM * sizeof(float),
                   hipMemcpyDeviceToDevice, stream);
    pad_copy<<<192, 256, 0, stream>>>(rel, ws + ORP);

    for (int l = 0; l < NL; ++l) {
        const float* xl = out + (size_t)l * NROWS * HDIM;
        float*       xn = out + (size_t)(l + 1) * NROWS * HDIM;
        float*  probs_l = probs_out + (size_t)l * BATCH * NHEAD * SEQ * SEQ;
        const float* Wqk_l = Wqk + (size_t)l * QKW * HDIM;
        const float* bqk_l = bqk + (size_t)l * QKW;
        const float* Wv_l  = Wv  + (size_t)l * HDIM * HDIM;
        const float* bv_l  = bv  + (size_t)l * HDIM;
        const float* Wo_l  = Wo  + (size_t)l * HDIM * HDIM;
        const float* bo_l  = bo  + (size_t)l * HDIM;
        const float* g_l   = lng + (size_t)l * HDIM;
        const float* b_l   = lnb + (size_t)l * HDIM;
        const float* W1_l  = W1  + (size_t)l * 2 * FFI * HDIM;
        const float* W2_l  = W2  + (size_t)l * HDIM * FFI;

        /* h = ln(x) */
        ln_rows<<<NROWS, 256, 0, stream>>>(xl, ws + OH);
        /* qk = h@Wqk^T + bqk ; v = h@Wv^T + bv */
        gemm_tn<true, false><<<dim3(QKW / 64, NROWS / 64), 256, 0, stream>>>(
            ws + OH, Wqk_l, bqk_l, nullptr, ws + OQK, NROWS, QKW, HDIM);
        gemm_tn<true, false><<<dim3(HDIM / 64, NROWS / 64), 256, 0, stream>>>(
            ws + OH, Wv_l, bv_l, nullptr, ws + OV, NROWS, HDIM, HDIM);
        /* pos = relpad@Wqk^T + bqk (64 rows, last row junk-but-unused) */
        gemm_tn<true, false><<<dim3(QKW / 64, 1), 256, 0, stream>>>(
            ws + ORP, Wqk_l, bqk_l, nullptr, ws + OPOS, 64, QKW, HDIM);
        /* CP / PC rel-position tensors */
        cp_kernel<<<dim3(BATCH * NHEAD, SEQ / 64), 256, 0, stream>>>(
            ws + OQK, ws + OPOS, ws + OCP);
        pc_kernel<<<dim3(BATCH * NHEAD, SEQ / 64), 256, 0, stream>>>(
            ws + OQK, ws + OPOS, ws + OPC);
        /* scores + softmax -> probs (d_out) */
        scores_softmax<<<dim3(BATCH * NHEAD, SEQ / 16), 256, 0, stream>>>(
            ws + OQK, ws + OCP, ws + OPC, pidx, mask, probs_l);
        /* ctx = probs @ v */
        ctx_kernel<<<dim3(BATCH * NHEAD, SEQ / 64), 256, 0, stream>>>(
            probs_l, ws + OV, ws + OCTX);
        /* t1 = ctx@Wo^T + bo */
        gemm_tn<true, false><<<dim3(HDIM / 64, NROWS / 64), 256, 0, stream>>>(
            ws + OCTX, Wo_l, bo_l, nullptr, ws + OT1, NROWS, HDIM, HDIM);
        /* x_mid = x + ln(t1)*g+b ; hh = ln(x_mid) */
        post_attn<<<NROWS, 256, 0, stream>>>(ws + OT1, xl, g_l, b_l,
                                             ws + OXM, ws + OHH);
        /* u1 = hh @ W1^T */
        gemm_tn<false, false><<<dim3(2 * FFI / 64, NROWS / 64), 256, 0, stream>>>(
            ws + OHH, W1_l, nullptr, nullptr, ws + OU1, NROWS, 2 * FFI, HDIM);
        /* u2 = ln(a * gelu(gate)) */
        act_ln<<<NROWS, 256, 0, stream>>>(ws + OU1, ws + OU2);
        /* x_next = x_mid + u2 @ W2^T  -> hidden_stack[l+1] */
        gemm_tn<false, true><<<dim3(HDIM / 64, NROWS / 64), 256, 0, stream>>>(
            ws + OU2, W2_l, nullptr, ws + OXM, xn, NROWS, HDIM, FFI);
    }
}

// Round 3
// 6818.414 us; speedup vs baseline: 1.4289x; 1.4289x over previous
//
#include <hip/hip_runtime.h>
#include <math.h>

#define NL    12
#define HDIM  768
#define NHEAD 12
#define DHEAD 64
#define FFI   2048
#define SEQ   512
#define BATCH 4
#define NROWS 2048
#define QKW   1536
#define SCALE 0.07216878364870323f
#define LNEPS 1e-7f
#define LO_SCALE 2048.0f
#define LO_INV   4.8828125e-4f

typedef _Float16 f16x8 __attribute__((ext_vector_type(8)));
typedef float    f32x4 __attribute__((ext_vector_type(4)));

/* ---- workspace byte offsets ---- */
#define OB_QK    0ull          /* f32 2048x1536 = 12582912 B */
#define OB_V     12582912ull   /* f32 2048x768  =  6291456 B */
#define OB_POS   18874368ull   /* f32 64x1536   =   393216 B */
#define OB_CP    19267584ull   /* f32 48*512*63 =  6193152 B */
#define OB_PC    25460736ull   /* f32 48*512*63 =  6193152 B */
/* u1 f32 2048x4096 = 33554432 B aliases [0 .. 33554432) (QK..PC all dead) */
#define OB_U1    0ull
#define OB_T1    33554432ull   /* f32 2048x768 */
#define OB_XM    39845888ull   /* f32 2048x768 */
#define OB_RELP  46137344ull   /* f32 64x768 = 196608 B */
#define OB_XH    46333952ull   /* f16 up to 2048x2048 = 8388608 B */
#define OB_XL    54722560ull
#define OB_WH    63111168ull   /* f16 up to 4096x768 = 6291456 B */
#define OB_WL    69402624ull
/* total 75694080 B ~= 75.7 MB */

#if defined(__has_builtin)
#if __has_builtin(__builtin_amdgcn_global_load_lds)
#define HAVE_GLL 1
#endif
#endif

__device__ __forceinline__ void gload_lds16(const _Float16* gp, _Float16* lp) {
#ifdef HAVE_GLL
    __builtin_amdgcn_global_load_lds(
        (const __attribute__((address_space(1))) void*)gp,
        (__attribute__((address_space(3))) void*)lp, 16, 0, 0);
#else
    *(f16x8*)lp = *(const f16x8*)gp;
#endif
}

__device__ __forceinline__ float block_reduce_sum_256(float v, float* sred) {
    #pragma unroll
    for (int off = 32; off > 0; off >>= 1) v += __shfl_down(v, off, 64);
    const int w = threadIdx.x >> 6;
    if ((threadIdx.x & 63) == 0) sred[w] = v;
    __syncthreads();
    float r = sred[0] + sred[1] + sred[2] + sred[3];
    __syncthreads();
    return r;
}

__device__ __forceinline__ void split_store(float x, _Float16* hi, _Float16* lo,
                                            size_t idx) {
    _Float16 h = (_Float16)x;
    hi[idx] = h;
    lo[idx] = (_Float16)((x - (float)h) * LO_SCALE);
}

/* pad relative_embedding (63x768) to 64x768 with a zero row */
__global__ __launch_bounds__(256) void pad_copy(const float* __restrict__ rel,
                                                float* __restrict__ relpad) {
    int i = blockIdx.x * 256 + threadIdx.x;
    relpad[i] = (i < 63 * HDIM) ? rel[i] : 0.f;
}

/* split a weight matrix (row-major [N][K] f32) into hi/lo f16 */
__global__ __launch_bounds__(256)
void wsplit(const float* __restrict__ W, _Float16* __restrict__ Wh,
            _Float16* __restrict__ Wl) {
    const size_t i = ((size_t)blockIdx.x * 256 + threadIdx.x) * 8;
    float4 a = *(const float4*)(W + i);
    float4 b = *(const float4*)(W + i + 4);
    float x[8] = {a.x, a.y, a.z, a.w, b.x, b.y, b.z, b.w};
    f16x8 h, l;
    #pragma unroll
    for (int j = 0; j < 8; ++j) {
        _Float16 hh = (_Float16)x[j];
        h[j] = hh;
        l[j] = (_Float16)((x[j] - (float)hh) * LO_SCALE);
    }
    *(f16x8*)(Wh + i) = h;
    *(f16x8*)(Wl + i) = l;
}

/* LayerNorm (no affine) -> split f16 hi/lo */
__global__ __launch_bounds__(256)
void ln_split(const float* __restrict__ in, _Float16* __restrict__ hi,
              _Float16* __restrict__ lo) {
    __shared__ float sred[4];
    const int row = blockIdx.x;
    const float* r = in + (size_t)row * HDIM;
    float v[3];
    #pragma unroll
    for (int i = 0; i < 3; ++i) v[i] = r[threadIdx.x + i * 256];
    float s = v[0] + v[1] + v[2];
    s = block_reduce_sum_256(s, sred);
    const float mean = s * (1.0f / HDIM);
    float q = 0.f;
    #pragma unroll
    for (int i = 0; i < 3; ++i) { float d = v[i] - mean; q += d * d; }
    q = block_reduce_sum_256(q, sred);
    const float rstd = 1.0f / sqrtf(q * (1.0f / HDIM) + LNEPS);
    #pragma unroll
    for (int i = 0; i < 3; ++i)
        split_store((v[i] - mean) * rstd, hi, lo,
                    (size_t)row * HDIM + threadIdx.x + i * 256);
}

/* ============ fp16x2 split GEMM: C[M,N] = A @ Bw^T (+bias) (+Res) ============
   A,B given as hi/lo f16 (lo pre-scaled by 2^11), row-major [M][K]/[N][K].
   128x128 tile, BK=32, 4 waves, mfma_f32_16x16x32_f16.
   LDS linear dest (global_load_lds), 2-bit XOR swizzle on source + read. */
template<bool HB, bool HR>
__global__ __launch_bounds__(256, 2)
void gemm_split(const _Float16* __restrict__ Ah, const _Float16* __restrict__ Al,
                const _Float16* __restrict__ Bh, const _Float16* __restrict__ Bl,
                const float* __restrict__ bias, const float* __restrict__ Res,
                float* __restrict__ C, int M, int N, int K) {
    __shared__ __align__(16) _Float16 sAh[128 * 32];
    __shared__ __align__(16) _Float16 sAl[128 * 32];
    __shared__ __align__(16) _Float16 sBh[128 * 32];
    __shared__ __align__(16) _Float16 sBl[128 * 32];
    const int t  = threadIdx.x;
    const int bm = blockIdx.y * 128;
    const int bn = blockIdx.x * 128;
    const int w  = t >> 6, l = t & 63;
    const int wr = (w >> 1) * 64, wc = (w & 1) * 64;
    const int r0 = t >> 2, s0 = t & 3;

    f32x4 acc1[4][4] = {};
    f32x4 acc2[4][4] = {};

    const int kg = l >> 4, lr = l & 15;

    for (int kt = 0; kt < K; kt += 32) {
        if (kt) __syncthreads();
        #pragma unroll
        for (int i = 0; i < 2; ++i) {
            const int row   = i * 64 + r0;
            const int scol  = ((s0 ^ (row & 3)) << 3) + kt;
            const size_t ga = (size_t)(bm + row) * K + scol;
            const size_t gb = (size_t)(bn + row) * K + scol;
            const int ld    = row * 32 + s0 * 8;
            gload_lds16(Ah + ga, sAh + ld);
            gload_lds16(Al + ga, sAl + ld);
            gload_lds16(Bh + gb, sBh + ld);
            gload_lds16(Bl + gb, sBl + ld);
        }
        __syncthreads();
        f16x8 a_h[4], a_l[4], b_h[4], b_l[4];
        #pragma unroll
        for (int i = 0; i < 4; ++i) {
            const int row = wr + i * 16 + lr;
            const int off = row * 32 + ((kg ^ (row & 3)) << 3);
            a_h[i] = *(const f16x8*)(sAh + off);
            a_l[i] = *(const f16x8*)(sAl + off);
            const int col  = wc + i * 16 + lr;
            const int offb = col * 32 + ((kg ^ (col & 3)) << 3);
            b_h[i] = *(const f16x8*)(sBh + offb);
            b_l[i] = *(const f16x8*)(sBl + offb);
        }
        #pragma unroll
        for (int i = 0; i < 4; ++i)
            #pragma unroll
            for (int j = 0; j < 4; ++j) {
                acc1[i][j] = __builtin_amdgcn_mfma_f32_16x16x32_f16(
                    a_h[i], b_h[j], acc1[i][j], 0, 0, 0);
                acc2[i][j] = __builtin_amdgcn_mfma_f32_16x16x32_f16(
                    a_h[i], b_l[j], acc2[i][j], 0, 0, 0);
                acc2[i][j] = __builtin_amdgcn_mfma_f32_16x16x32_f16(
                    a_l[i], b_h[j], acc2[i][j], 0, 0, 0);
            }
    }
    #pragma unroll
    for (int i = 0; i < 4; ++i)
        #pragma unroll
        for (int j = 0; j < 4; ++j)
            #pragma unroll
            for (int r = 0; r < 4; ++r) {
                const int grow = bm + wr + i * 16 + kg * 4 + r;
                const int gcol = bn + wc + j * 16 + lr;
                float v = acc1[i][j][r] + acc2[i][j][r] * LO_INV;
                if (HB) v += bias[gcol];
                if (HR) v += Res[(size_t)grow * N + gcol];
                C[(size_t)grow * N + gcol] = v;
            }
}

/* f32 tiled GEMM kept for the tiny pos matmul (64x1536x768) */
template<bool HB, bool HR>
__global__ __launch_bounds__(256)
void gemm_tn(const float* __restrict__ A, const float* __restrict__ Bw,
             const float* __restrict__ bias, const float* __restrict__ Res,
             float* __restrict__ C, int M, int N, int K) {
    __shared__ float As[16][68];
    __shared__ float Bs[16][68];
    const int bm = blockIdx.y * 64;
    const int bn = blockIdx.x * 64;
    const int ty = threadIdx.x >> 4;
    const int tx = threadIdx.x & 15;
    const int lr = threadIdx.x >> 2;
    const int lc = (threadIdx.x & 3) * 4;
    const float* Aptr = A + (size_t)(bm + lr) * K + lc;
    const float* Bptr = Bw + (size_t)(bn + lr) * K + lc;
    float acc[4][4] = {};
    for (int kt = 0; kt < K; kt += 16) {
        float4 a4 = *(const float4*)(Aptr + kt);
        float4 b4 = *(const float4*)(Bptr + kt);
        As[lc + 0][lr] = a4.x; As[lc + 1][lr] = a4.y;
        As[lc + 2][lr] = a4.z; As[lc + 3][lr] = a4.w;
        Bs[lc + 0][lr] = b4.x; Bs[lc + 1][lr] = b4.y;
        Bs[lc + 2][lr] = b4.z; Bs[lc + 3][lr] = b4.w;
        __syncthreads();
        #pragma unroll
        for (int k = 0; k < 16; ++k) {
            float4 av = *(const float4*)&As[k][ty * 4];
            float4 bv = *(const float4*)&Bs[k][tx * 4];
            float a[4] = {av.x, av.y, av.z, av.w};
            float b[4] = {bv.x, bv.y, bv.z, bv.w};
            #pragma unroll
            for (int i = 0; i < 4; ++i)
                #pragma unroll
                for (int j = 0; j < 4; ++j) acc[i][j] += a[i] * b[j];
        }
        __syncthreads();
    }
    #pragma unroll
    for (int i = 0; i < 4; ++i) {
        const int r = bm + ty * 4 + i;
        #pragma unroll
        for (int j = 0; j < 4; ++j) {
            const int c = bn + tx * 4 + j;
            float v = acc[i][j];
            if (HB) v += bias[c];
            if (HR) v += Res[(size_t)r * N + c];
            C[(size_t)r * N + c] = v;
        }
    }
}

/* CP[bh,q,kb] = scale * sum_d q[b,h,q,d]*kpos[kb,h,d] */
__global__ __launch_bounds__(256)
void cp_kernel(const float* __restrict__ qk, const float* __restrict__ pos,
               float* __restrict__ CP) {
    const int bh = blockIdx.x;
    const int b = bh / NHEAD, hd = bh % NHEAD;
    const int qt = blockIdx.y * 64;
    __shared__ float kp[64][65];
    __shared__ float qs[64][65];
    for (int i = threadIdx.x; i < 64 * 64; i += 256) {
        int kb = i >> 6, d = i & 63;
        kp[kb][d] = (kb < 63) ? pos[(size_t)kb * QKW + HDIM + hd * 64 + d] : 0.f;
    }
    for (int i = threadIdx.x; i < 64 * 64; i += 256) {
        int q = i >> 6, d = i & 63;
        qs[q][d] = qk[((size_t)(qt + q) * BATCH + b) * QKW + hd * 64 + d];
    }
    __syncthreads();
    const int ql = threadIdx.x >> 2;
    const int kb0 = threadIdx.x & 3;
    float s[16] = {};
    #pragma unroll
    for (int d = 0; d < 64; ++d) {
        float qr = qs[ql][d];
        #pragma unroll
        for (int jj = 0; jj < 16; ++jj) s[jj] += qr * kp[kb0 + jj * 4][d];
    }
    #pragma unroll
    for (int jj = 0; jj < 16; ++jj) {
        int kb = kb0 + jj * 4;
        if (kb < 63)
            CP[((size_t)bh * SEQ + qt + ql) * 63 + kb] = s[jj] * SCALE;
    }
}

/* PC[bh,qb,k] = scale * sum_d k[b,h,k,d]*qpos[qb,h,d] */
__global__ __launch_bounds__(256)
void pc_kernel(const float* __restrict__ qk, const float* __restrict__ pos,
               float* __restrict__ PC) {
    const int bh = blockIdx.x;
    const int b = bh / NHEAD, hd = bh % NHEAD;
    const int kt = blockIdx.y * 64;
    __shared__ float qp[64][65];
    __shared__ float ks[64][65];
    for (int i = threadIdx.x; i < 64 * 64; i += 256) {
        int qb = i >> 6, d = i & 63;
        qp[qb][d] = (qb < 63) ? pos[(size_t)qb * QKW + hd * 64 + d] : 0.f;
    }
    for (int i = threadIdx.x; i < 64 * 64; i += 256) {
        int kl = i >> 6, d = i & 63;
        ks[kl][d] = qk[((size_t)(kt + kl) * BATCH + b) * QKW + HDIM + hd * 64 + d];
    }
    __syncthreads();
    const int kl = threadIdx.x & 63;
    const int qb0 = threadIdx.x >> 6;
    float s[16] = {};
    #pragma unroll
    for (int d = 0; d < 64; ++d) {
        float kr = ks[kl][d];
        #pragma unroll
        for (int jj = 0; jj < 16; ++jj) s[jj] += kr * qp[qb0 + jj * 4][d];
    }
    #pragma unroll
    for (int jj = 0; jj < 16; ++jj) {
        int qb = qb0 + jj * 4;
        if (qb < 63)
            PC[((size_t)bh * 63 + qb) * SEQ + kt + kl] = s[jj] * SCALE;
    }
}

/* scores + rel-pos gathers + mask + softmax -> probs (d_out) */
__global__ __launch_bounds__(256)
void scores_softmax(const float* __restrict__ qk, const float* __restrict__ CP,
                    const float* __restrict__ PC, const int* __restrict__ idx,
                    const unsigned char* __restrict__ mask,
                    float* __restrict__ probs) {
    const int bh = blockIdx.x;
    const int b = bh / NHEAD, hd = bh % NHEAD;
    const int qbase = blockIdx.y * 16;
    const int row = threadIdx.x >> 4;
    const int ln = threadIdx.x & 15;
    __shared__ float qs[16][65];
    __shared__ float ks[64][65];
    for (int i = threadIdx.x; i < 16 * 64; i += 256) {
        int q = i >> 6, d = i & 63;
        qs[q][d] = qk[((size_t)(qbase + q) * BATCH + b) * QKW + hd * 64 + d];
    }
    float sc[32];
    for (int kt = 0; kt < 8; ++kt) {
        __syncthreads();
        for (int i = threadIdx.x; i < 64 * 64; i += 256) {
            int kl = i >> 6, d = i & 63;
            ks[kl][d] = qk[((size_t)(kt * 64 + kl) * BATCH + b) * QKW + HDIM + hd * 64 + d];
        }
        __syncthreads();
        float s0 = 0.f, s1 = 0.f, s2 = 0.f, s3 = 0.f;
        #pragma unroll
        for (int d = 0; d < 64; ++d) {
            float qr = qs[row][d];
            s0 += qr * ks[ln +  0][d];
            s1 += qr * ks[ln + 16][d];
            s2 += qr * ks[ln + 32][d];
            s3 += qr * ks[ln + 48][d];
        }
        sc[kt * 4 + 0] = s0; sc[kt * 4 + 1] = s1;
        sc[kt * 4 + 2] = s2; sc[kt * 4 + 3] = s3;
    }
    const int* idxrow = idx + (size_t)(qbase + row) * SEQ;
    const float* CProw = CP + ((size_t)bh * SEQ + qbase + row) * 63;
    #pragma unroll
    for (int j = 0; j < 32; ++j) {
        const int col = (j >> 2) * 64 + (j & 3) * 16 + ln;
        const int ix = idxrow[col];
        float s = sc[j] * SCALE + CProw[ix] + PC[((size_t)bh * 63 + ix) * SEQ + col];
        if (mask[b * SEQ + col]) s = -INFINITY;
        sc[j] = s;
    }
    float mx = sc[0];
    #pragma unroll
    for (int j = 1; j < 32; ++j) mx = fmaxf(mx, sc[j]);
    #pragma unroll
    for (int off = 1; off < 16; off <<= 1) mx = fmaxf(mx, __shfl_xor(mx, off, 16));
    float sum = 0.f;
    #pragma unroll
    for (int j = 0; j < 32; ++j) { float e = expf(sc[j] - mx); sc[j] = e; sum += e; }
    #pragma unroll
    for (int off = 1; off < 16; off <<= 1) sum += __shfl_xor(sum, off, 16);
    const float inv = 1.0f / sum;
    float* prow = probs + ((size_t)bh * SEQ + qbase + row) * SEQ;
    #pragma unroll
    for (int j = 0; j < 32; ++j) {
        const int col = (j >> 2) * 64 + (j & 3) * 16 + ln;
        float p = sc[j] * inv;
        if (mask[b * SEQ + col]) p = 0.f;
        prow[col] = p;
    }
}

/* ctx = probs @ v -> split f16 hi/lo directly */
__global__ __launch_bounds__(256)
void ctx_split(const float* __restrict__ probs, const float* __restrict__ vbuf,
               _Float16* __restrict__ Xh, _Float16* __restrict__ Xl) {
    const int bh = blockIdx.x;
    const int b = bh / NHEAD, hd = bh % NHEAD;
    const int qt = blockIdx.y * 64;
    __shared__ float ps[32][65];
    __shared__ float vs[32][65];
    const int ty = threadIdx.x >> 4, tx = threadIdx.x & 15;
    float acc[4][4] = {};
    const float* prow = probs + ((size_t)bh * SEQ + qt) * SEQ;
    for (int kt = 0; kt < 16; ++kt) {
        for (int i = threadIdx.x; i < 64 * 32; i += 256) {
            int q = i >> 5, kk = i & 31;
            ps[kk][q] = prow[(size_t)q * SEQ + kt * 32 + kk];
        }
        for (int i = threadIdx.x; i < 32 * 64; i += 256) {
            int kk = i >> 6, d = i & 63;
            vs[kk][d] = vbuf[((size_t)(kt * 32 + kk) * BATCH + b) * HDIM + hd * 64 + d];
        }
        __syncthreads();
        #pragma unroll
        for (int k = 0; k < 32; ++k) {
            float a[4], bb[4];
            #pragma unroll
            for (int i = 0; i < 4; ++i) a[i] = ps[k][ty * 4 + i];
            #pragma unroll
            for (int j = 0; j < 4; ++j) bb[j] = vs[k][tx * 4 + j];
            #pragma unroll
            for (int i = 0; i < 4; ++i)
                #pragma unroll
                for (int j = 0; j < 4; ++j) acc[i][j] += a[i] * bb[j];
        }
        __syncthreads();
    }
    #pragma unroll
    for (int i = 0; i < 4; ++i)
        #pragma unroll
        for (int j = 0; j < 4; ++j)
            split_store(acc[i][j], Xh, Xl,
                ((size_t)(qt + ty * 4 + i) * BATCH + b) * HDIM + hd * 64 + tx * 4 + j);
}

/* x_mid = x + ln(t1)*g + b ; split(ln(x_mid)) -> Hh/Hl */
__global__ __launch_bounds__(256)
void post_attn(const float* __restrict__ t1, const float* __restrict__ xprev,
               const float* __restrict__ g, const float* __restrict__ bb,
               float* __restrict__ xmid, _Float16* __restrict__ Hh,
               _Float16* __restrict__ Hl) {
    __shared__ float sred[4];
    const int row = blockIdx.x;
    const float* tr = t1 + (size_t)row * HDIM;
    float v[3];
    #pragma unroll
    for (int i = 0; i < 3; ++i) v[i] = tr[threadIdx.x + i * 256];
    float s = v[0] + v[1] + v[2];
    s = block_reduce_sum_256(s, sred);
    const float mean = s * (1.0f / HDIM);
    float q = 0.f;
    #pragma unroll
    for (int i = 0; i < 3; ++i) { float d = v[i] - mean; q += d * d; }
    q = block_reduce_sum_256(q, sred);
    const float rstd = 1.0f / sqrtf(q * (1.0f / HDIM) + LNEPS);
    float xm[3];
    #pragma unroll
    for (int i = 0; i < 3; ++i) {
        const int c = threadIdx.x + i * 256;
        xm[i] = xprev[(size_t)row * HDIM + c] + ((v[i] - mean) * rstd * g[c] + bb[c]);
        xmid[(size_t)row * HDIM + c] = xm[i];
    }
    float s2 = xm[0] + xm[1] + xm[2];
    s2 = block_reduce_sum_256(s2, sred);
    const float mean2 = s2 * (1.0f / HDIM);
    float q2 = 0.f;
    #pragma unroll
    for (int i = 0; i < 3; ++i) { float d = xm[i] - mean2; q2 += d * d; }
    q2 = block_reduce_sum_256(q2, sred);
    const float rstd2 = 1.0f / sqrtf(q2 * (1.0f / HDIM) + LNEPS);
    #pragma unroll
    for (int i = 0; i < 3; ++i)
        split_store((xm[i] - mean2) * rstd2, Hh, Hl,
                    (size_t)row * HDIM + threadIdx.x + i * 256);
}

/* u2 = ln( a * gelu_new(gate) ) -> split f16 hi/lo */
__global__ __launch_bounds__(256)
void act_ln(const float* __restrict__ u1, _Float16* __restrict__ Uh,
            _Float16* __restrict__ Ul) {
    __shared__ float sred[4];
    const int row = blockIdx.x;
    const float* r = u1 + (size_t)row * (2 * FFI);
    float t[8];
    #pragma unroll
    for (int i = 0; i < 8; ++i) {
        const int c = threadIdx.x + i * 256;
        const float a  = r[c];
        const float gt = r[FFI + c];
        const float x3 = gt + 0.044715f * gt * gt * gt;
        const float th = tanhf(0.7978845608028654f * x3);
        t[i] = a * 0.5f * gt * (1.0f + th);
    }
    float s = 0.f;
    #pragma unroll
    for (int i = 0; i < 8; ++i) s += t[i];
    s = block_reduce_sum_256(s, sred);
    const float mean = s * (1.0f / FFI);
    float q = 0.f;
    #pragma unroll
    for (int i = 0; i < 8; ++i) { float d = t[i] - mean; q += d * d; }
    q = block_reduce_sum_256(q, sred);
    const float rstd = 1.0f / sqrtf(q * (1.0f / FFI) + LNEPS);
    #pragma unroll
    for (int i = 0; i < 8; ++i)
        split_store((t[i] - mean) * rstd, Uh, Ul,
                    (size_t)row * FFI + threadIdx.x + i * 256);
}

extern "C" void kernel_launch(void* const* d_in, const int* in_sizes, int n_in,
                              void* d_out, int out_size, void* d_ws, size_t ws_size,
                              hipStream_t stream) {
    const float*         x0   = (const float*)d_in[0];
    const unsigned char* mask = (const unsigned char*)d_in[1];
    const float*         rel  = (const float*)d_in[2];
    const int*           pidx = (const int*)d_in[3];
    const float*         Wqk  = (const float*)d_in[4];
    const float*         bqk  = (const float*)d_in[5];
    const float*         Wv   = (const float*)d_in[6];
    const float*         bv   = (const float*)d_in[7];
    const float*         Wo   = (const float*)d_in[8];
    const float*         bo   = (const float*)d_in[9];
    const float*         lng  = (const float*)d_in[10];
    const float*         lnb  = (const float*)d_in[11];
    const float*         W1   = (const float*)d_in[12];
    const float*         W2   = (const float*)d_in[13];

    float* out = (float*)d_out;
    char*  wsb = (char*)d_ws;
    float* probs_out = out + (size_t)(NL + 1) * NROWS * HDIM;

    float*    f_qk  = (float*)(wsb + OB_QK);
    float*    f_v   = (float*)(wsb + OB_V);
    float*    f_pos = (float*)(wsb + OB_POS);
    float*    f_cp  = (float*)(wsb + OB_CP);
    float*    f_pc  = (float*)(wsb + OB_PC);
    float*    f_u1  = (float*)(wsb + OB_U1);
    float*    f_t1  = (float*)(wsb + OB_T1);
    float*    f_xm  = (float*)(wsb + OB_XM);
    float*    f_rp  = (float*)(wsb + OB_RELP);
    _Float16* Xh    = (_Float16*)(wsb + OB_XH);
    _Float16* Xl    = (_Float16*)(wsb + OB_XL);
    _Float16* Wh    = (_Float16*)(wsb + OB_WH);
    _Float16* Wl    = (_Float16*)(wsb + OB_WL);

    hipMemcpyAsync(out, x0, (size_t)NROWS * HDIM * sizeof(float),
                   hipMemcpyDeviceToDevice, stream);
    pad_copy<<<192, 256, 0, stream>>>(rel, f_rp);

    for (int l = 0; l < NL; ++l) {
        const float* xl = out + (size_t)l * NROWS * HDIM;
        float*       xn = out + (size_t)(l + 1) * NROWS * HDIM;
        float*  probs_l = probs_out + (size_t)l * BATCH * NHEAD * SEQ * SEQ;
        const float* Wqk_l = Wqk + (size_t)l * QKW * HDIM;
        const float* bqk_l = bqk + (size_t)l * QKW;
        const float* Wv_l  = Wv  + (size_t)l * HDIM * HDIM;
        const float* bv_l  = bv  + (size_t)l * HDIM;
        const float* Wo_l  = Wo  + (size_t)l * HDIM * HDIM;
        const float* bo_l  = bo  + (size_t)l * HDIM;
        const float* g_l   = lng + (size_t)l * HDIM;
        const float* b_l   = lnb + (size_t)l * HDIM;
        const float* W1_l  = W1  + (size_t)l * 2 * FFI * HDIM;
        const float* W2_l  = W2  + (size_t)l * HDIM * FFI;

        /* h = ln(x) -> split */
        ln_split<<<NROWS, 256, 0, stream>>>(xl, Xh, Xl);
        /* qk = h@Wqk^T + bqk */
        wsplit<<<QKW * HDIM / 2048, 256, 0, stream>>>(Wqk_l, Wh, Wl);
        gemm_split<true, false><<<dim3(QKW / 128, NROWS / 128), 256, 0, stream>>>(
            Xh, Xl, Wh, Wl, bqk_l, nullptr, f_qk, NROWS, QKW, HDIM);
        /* v = h@Wv^T + bv */
        wsplit<<<HDIM * HDIM / 2048, 256, 0, stream>>>(Wv_l, Wh, Wl);
        gemm_split<true, false><<<dim3(HDIM / 128, NROWS / 128), 256, 0, stream>>>(
            Xh, Xl, Wh, Wl, bv_l, nullptr, f_v, NROWS, HDIM, HDIM);
        /* pos = relpad@Wqk^T + bqk (tiny, f32) */
        gemm_tn<true, false><<<dim3(QKW / 64, 1), 256, 0, stream>>>(
            f_rp, Wqk_l, bqk_l, nullptr, f_pos, 64, QKW, HDIM);
        cp_kernel<<<dim3(BATCH * NHEAD, SEQ / 64), 256, 0, stream>>>(f_qk, f_pos, f_cp);
        pc_kernel<<<dim3(BATCH * NHEAD, SEQ / 64), 256, 0, stream>>>(f_qk, f_pos, f_pc);
        scores_softmax<<<dim3(BATCH * NHEAD, SEQ / 16), 256, 0, stream>>>(
            f_qk, f_cp, f_pc, pidx, mask, probs_l);
        /* ctx = probs @ v -> split */
        ctx_split<<<dim3(BATCH * NHEAD, SEQ / 64), 256, 0, stream>>>(probs_l, f_v, Xh, Xl);
        /* t1 = ctx@Wo^T + bo */
        wsplit<<<HDIM * HDIM / 2048, 256, 0, stream>>>(Wo_l, Wh, Wl);
        gemm_split<true, false><<<dim3(HDIM / 128, NROWS / 128), 256, 0, stream>>>(
            Xh, Xl, Wh, Wl, bo_l, nullptr, f_t1, NROWS, HDIM, HDIM);
        /* x_mid = x + ln(t1)*g+b ; split(ln(x_mid)) */
        post_attn<<<NROWS, 256, 0, stream>>>(f_t1, xl, g_l, b_l, f_xm, Xh, Xl);
        /* u1 = hh @ W1^T */
        wsplit<<<2 * FFI * HDIM / 2048, 256, 0, stream>>>(W1_l, Wh, Wl);
        gemm_split<false, false><<<dim3(2 * FFI / 128, NROWS / 128), 256, 0, stream>>>(
            Xh, Xl, Wh, Wl, nullptr, nullptr, f_u1, NROWS, 2 * FFI, HDIM);
        /* u2 = ln(a*gelu(gate)) -> split */
        act_ln<<<NROWS, 256, 0, stream>>>(f_u1, Xh, Xl);
        /* x_next = x_mid + u2 @ W2^T */
        wsplit<<<HDIM * FFI / 2048, 256, 0, stream>>>(W2_l, Wh, Wl);
        gemm_split<false, true><<<dim3(HDIM / 128, NROWS / 128), 256, 0, stream>>>(
            Xh, Xl, Wh, Wl, nullptr, f_xm, xn, NROWS, HDIM, FFI);
    }
}